// Round 1
// 588.400 us; speedup vs baseline: 1.3270x; 1.3270x over previous
//
#include <hip/hip_runtime.h>
#include <math.h>

// XOR-swizzled LDS addressing, pitch 64 (no pad needed): bank-conflict-free
// b128 transposed stores, <=2-way reads.  tok' = tok ^ (ch bits 2..4).
__device__ __forceinline__ int SW64(int ch, int t)  { return (ch << 6) + (t ^ (ch & 28)); }
__device__ __forceinline__ int SW128(int ch, int t) { return (ch << 7) + (t ^ (ch & 28)); }

// ---------------------------------------------------------------------------
// Kernel AB: fc1 (768->64) + 8x 64x64 chain + residual + exact GELU
// 256 threads, 64 tokens/block, 4x4 micro-tile. Two 16KB LDS buffers that
// swap roles (act/weights) each layer -> 5 blocks/CU. Register-transposed
// float4 LDS stores + XOR swizzle kill the 8-way write conflicts.
// ---------------------------------------------------------------------------
__global__ __launch_bounds__(256, 4) void k_fc1_chain(
    const float* __restrict__ x, const float* __restrict__ fc1_w,
    const float* __restrict__ fc1_b, const float* __restrict__ conv_w,
    const float* __restrict__ conv_b, float* __restrict__ xs)
{
    __shared__ float lds[2 * 4096];
    float* bufA = lds;          // act / fc1 A-tile
    float* bufB = lds + 4096;   // weights / fc1 B-tile

    const int tid = threadIdx.x;
    const int tx = tid & 15;
    const int ty = tid >> 4;
    const int t0 = blockIdx.x * 64;
    const int c0 = tx * 4;   // channel/out base
    const int r0 = ty * 4;   // token/row base (4 consecutive rows -> b128 stores)

    float acc[4][4];
#pragma unroll
    for (int i = 0; i < 4; ++i)
#pragma unroll
        for (int j = 0; j < 4; ++j) acc[i][j] = 0.f;

    // ---- fc1: K = 768 in 12 tiles, register-prefetched ----
    float xr[4][4], wr1[4][4];
#pragma unroll
    for (int i = 0; i < 4; ++i) {
        const float4 v = *(const float4*)(x + (size_t)(t0 + r0 + i) * 768 + c0);
        xr[i][0] = v.x; xr[i][1] = v.y; xr[i][2] = v.z; xr[i][3] = v.w;
        const float4 u = *(const float4*)(fc1_w + (size_t)(r0 + i) * 768 + c0);
        wr1[i][0] = u.x; wr1[i][1] = u.y; wr1[i][2] = u.z; wr1[i][3] = u.w;
    }

    for (int k0 = 0; k0 < 768; k0 += 64) {
#pragma unroll
        for (int j = 0; j < 4; ++j) {
            float4 s; s.x = xr[0][j]; s.y = xr[1][j]; s.z = xr[2][j]; s.w = xr[3][j];
            *(float4*)(bufA + SW64(c0 + j, r0)) = s;
            float4 t; t.x = wr1[0][j]; t.y = wr1[1][j]; t.z = wr1[2][j]; t.w = wr1[3][j];
            *(float4*)(bufB + SW64(c0 + j, r0)) = t;
        }
        __syncthreads();

        if (k0 + 64 < 768) {  // prefetch next tile under the compute window
#pragma unroll
            for (int i = 0; i < 4; ++i) {
                const float4 v = *(const float4*)(x + (size_t)(t0 + r0 + i) * 768 + k0 + 64 + c0);
                xr[i][0] = v.x; xr[i][1] = v.y; xr[i][2] = v.z; xr[i][3] = v.w;
                const float4 u = *(const float4*)(fc1_w + (size_t)(r0 + i) * 768 + k0 + 64 + c0);
                wr1[i][0] = u.x; wr1[i][1] = u.y; wr1[i][2] = u.z; wr1[i][3] = u.w;
            }
        }

#pragma unroll 16
        for (int k = 0; k < 64; ++k) {
            const float4 a4 = *(const float4*)(bufA + SW64(k, r0));
            const float4 b4 = *(const float4*)(bufB + SW64(k, c0));
            const float a[4] = {a4.x, a4.y, a4.z, a4.w};
            const float b[4] = {b4.x, b4.y, b4.z, b4.w};
#pragma unroll
            for (int i = 0; i < 4; ++i)
#pragma unroll
                for (int j = 0; j < 4; ++j) acc[i][j] = fmaf(a[i], b[j], acc[i][j]);
        }
        __syncthreads();
    }

    // fc1 bias -> act into bufA; stage W0 into bufB
#pragma unroll
    for (int j = 0; j < 4; ++j) {
        const float b = fc1_b[c0 + j];
        float4 s;
        s.x = acc[0][j] + b; s.y = acc[1][j] + b;
        s.z = acc[2][j] + b; s.w = acc[3][j] + b;
        *(float4*)(bufA + SW64(c0 + j, r0)) = s;
    }
    {
        float wr[4][4];
#pragma unroll
        for (int i = 0; i < 4; ++i) {
            const float4 v = *(const float4*)(conv_w + (r0 + i) * 64 + c0);
            wr[i][0] = v.x; wr[i][1] = v.y; wr[i][2] = v.z; wr[i][3] = v.w;
        }
#pragma unroll
        for (int j = 0; j < 4; ++j) {
            float4 s; s.x = wr[0][j]; s.y = wr[1][j]; s.z = wr[2][j]; s.w = wr[3][j];
            *(float4*)(bufB + SW64(c0 + j, r0)) = s;
        }
    }
    __syncthreads();

    float* cur = bufA;   // activations
    float* wb  = bufB;   // weights
    float res[4][4];

    for (int l = 0; l < 8; ++l) {
        float wr[4][4];
        if (l < 7) {  // prefetch W_{l+1} under compute
#pragma unroll
            for (int i = 0; i < 4; ++i) {
                const float4 v = *(const float4*)(conv_w + (l + 1) * 4096 + (r0 + i) * 64 + c0);
                wr[i][0] = v.x; wr[i][1] = v.y; wr[i][2] = v.z; wr[i][3] = v.w;
            }
        }
#pragma unroll
        for (int i = 0; i < 4; ++i)
#pragma unroll
            for (int j = 0; j < 4; ++j) acc[i][j] = 0.f;
#pragma unroll 16
        for (int k = 0; k < 64; ++k) {
            const float4 a4 = *(const float4*)(cur + SW64(k, r0));
            const float4 b4 = *(const float4*)(wb + SW64(k, c0));
            const float a[4] = {a4.x, a4.y, a4.z, a4.w};
            const float b[4] = {b4.x, b4.y, b4.z, b4.w};
#pragma unroll
            for (int i = 0; i < 4; ++i)
#pragma unroll
                for (int j = 0; j < 4; ++j) acc[i][j] = fmaf(a[i], b[j], acc[i][j]);
        }
#pragma unroll
        for (int i = 0; i < 4; ++i)
#pragma unroll
            for (int j = 0; j < 4; ++j) acc[i][j] += conv_b[l * 64 + c0 + j];

        if (l == 5) {
#pragma unroll
            for (int i = 0; i < 4; ++i)
#pragma unroll
                for (int j = 0; j < 4; ++j) res[i][j] = acc[i][j];
        }
        if (l < 7) {
            __syncthreads();  // all reads of cur/wb done
#pragma unroll
            for (int j = 0; j < 4; ++j) {
                float4 s; s.x = acc[0][j]; s.y = acc[1][j]; s.z = acc[2][j]; s.w = acc[3][j];
                *(float4*)(wb + SW64(c0 + j, r0)) = s;          // act over dead W_l
                float4 t; t.x = wr[0][j]; t.y = wr[1][j]; t.z = wr[2][j]; t.w = wr[3][j];
                *(float4*)(cur + SW64(c0 + j, r0)) = t;         // W_{l+1} over dead act
            }
            float* tmp = cur; cur = wb; wb = tmp;
            __syncthreads();
        }
    }

    // epilogue: residual (h after layer 5) + exact GELU, token-major store
#pragma unroll
    for (int i = 0; i < 4; ++i) {
        float4 g4;
        float v;
        v = acc[i][0] + res[i][0]; g4.x = 0.5f * v * (1.f + erff(v * 0.70710678118654752f));
        v = acc[i][1] + res[i][1]; g4.y = 0.5f * v * (1.f + erff(v * 0.70710678118654752f));
        v = acc[i][2] + res[i][2]; g4.z = 0.5f * v * (1.f + erff(v * 0.70710678118654752f));
        v = acc[i][3] + res[i][3]; g4.w = 0.5f * v * (1.f + erff(v * 0.70710678118654752f));
        *(float4*)(xs + (size_t)(t0 + r0 + i) * 64 + c0) = g4;
    }
}

// ---------------------------------------------------------------------------
// Kernel C: qkv. 4 output-channel groups of 12 -> 4x the waves of the old
// version (16/CU). xs read planar (free reshape reinterpretation).
// ---------------------------------------------------------------------------
__global__ __launch_bounds__(256) void k_qkv(
    const float* __restrict__ xs, const float* __restrict__ qkv_w,
    const float* __restrict__ qkv_b, float* __restrict__ qkv)
{
    __shared__ float wq[12 * 64];
    __shared__ float qb[12];
    const int tid = threadIdx.x;
    const int g = blockIdx.y;
    for (int i = tid; i < 768; i += 256) wq[i] = qkv_w[g * 768 + i];
    if (tid < 12) qb[tid] = qkv_b[g * 12 + tid];
    __syncthreads();

    const int p = blockIdx.x * 256 + tid;
    float acc[12];
#pragma unroll
    for (int n = 0; n < 12; ++n) acc[n] = qb[n];

    for (int c = 0; c < 64; c += 4) {
        const float xv0 = xs[(c + 0) * 65536 + p];
        const float xv1 = xs[(c + 1) * 65536 + p];
        const float xv2 = xs[(c + 2) * 65536 + p];
        const float xv3 = xs[(c + 3) * 65536 + p];
#pragma unroll
        for (int n = 0; n < 12; ++n) {
            const float4 w4 = *(const float4*)(wq + n * 64 + c);
            acc[n] += xv0 * w4.x + xv1 * w4.y + xv2 * w4.z + xv3 * w4.w;
        }
    }
#pragma unroll
    for (int n = 0; n < 12; ++n) qkv[(size_t)(g * 12 + n) * 65536 + p] = acc[n];
}

// ---------------------------------------------------------------------------
// Kernel D: shift-conv + dw-conv + rpb + softmax(9) + weighted V, then proj.
// One thread per (pixel, head): 32 px x 8 heads per 256-thread block,
// grid 2048 -> 8x the parallelism of the old one-thread-per-pixel version.
// proj phase: 32 px x 8 d-groups, 8 outputs/thread.
// ---------------------------------------------------------------------------
__global__ __launch_bounds__(256) void k_attn(
    const float* __restrict__ qkv, const float* __restrict__ dep1_w,
    const float* __restrict__ dep_b, const float* __restrict__ dep1_b,
    const float* __restrict__ rpb, const float* __restrict__ proj_w,
    const float* __restrict__ proj_b, float* __restrict__ obuf)
{
    __shared__ float s_d1w[162];
    __shared__ float s_db[18];
    __shared__ float s_d1b[18];
    __shared__ float s_rpb[72];
    __shared__ float s_pw[1024];
    __shared__ float s_pb[64];
    __shared__ float s_o[32 * 17];   // [px][16 vals], pitch 17

    const int tid = threadIdx.x;
    if (tid < 162) s_d1w[tid] = dep1_w[tid];
    if (tid < 18) { s_db[tid] = dep_b[tid]; s_d1b[tid] = dep1_b[tid]; }
    if (tid < 72) s_rpb[tid] = rpb[tid];
    for (int i = tid; i < 1024; i += 256) s_pw[i] = proj_w[i];
    if (tid < 64) s_pb[tid] = proj_b[tid];
    __syncthreads();

    const int px = tid & 31;
    const int nh = tid >> 5;
    const int p = blockIdx.x * 32 + px;
    const int h = p >> 11;
    const int w = p & 2047;

    int np[9];
    float vmask[9];
#pragma unroll
    for (int t = 0; t < 9; ++t) {
        const int dh = t / 3 - 1, dw = t % 3 - 1;
        const int hh = h + dh, ww = w + dw;
        const bool ok = ((unsigned)hh < 32u) && ((unsigned)ww < 2048u);
        np[t] = ok ? (hh * 2048 + ww) : p;
        vmask[t] = ok ? 1.f : 0.f;
    }

    const float* base = qkv + nh * 6 * 65536;
    const float q0 = base[p];
    const float q1 = base[65536 + p];

    float kn[2][9];
#pragma unroll
    for (int c = 0; c < 2; ++c)
#pragma unroll
        for (int t = 0; t < 9; ++t)
            kn[c][t] = base[(2 + c) * 65536 + np[t]] * vmask[t];

    float lg[9];
#pragma unroll
    for (int i = 0; i < 9; ++i) {
        float s = 0.f;
#pragma unroll
        for (int c = 0; c < 2; ++c) {
            const int o = c * 9 + i;
            float conv = 0.f;
#pragma unroll
            for (int t = 0; t < 9; ++t) conv = fmaf(kn[c][t], s_d1w[o * 9 + t], conv);
            const float k6 = kn[c][i] + conv + s_db[o] + s_d1b[o] + s_rpb[nh * 9 + i];
            s = fmaf((c == 0 ? q0 : q1), k6, s);
        }
        lg[i] = s * 0.35355339059327373f;  // (C_HID/NH)^-0.5 = 8^-0.5
    }
    float m = lg[0];
#pragma unroll
    for (int i = 1; i < 9; ++i) m = fmaxf(m, lg[i]);
    float sum = 0.f;
#pragma unroll
    for (int i = 0; i < 9; ++i) { lg[i] = expf(lg[i] - m); sum += lg[i]; }
    const float inv = 1.f / sum;

    float vn[2][9];
#pragma unroll
    for (int c = 0; c < 2; ++c)
#pragma unroll
        for (int t = 0; t < 9; ++t)
            vn[c][t] = base[(4 + c) * 65536 + np[t]] * vmask[t];

#pragma unroll
    for (int c = 0; c < 2; ++c) {
        float ov = 0.f;
#pragma unroll
        for (int i = 0; i < 9; ++i) {
            const int o = c * 9 + i;
            float conv = 0.f;
#pragma unroll
            for (int t = 0; t < 9; ++t) conv = fmaf(vn[c][t], s_d1w[o * 9 + t], conv);
            const float v6 = vn[c][i] + conv + s_db[o] + s_d1b[o];
            ov = fmaf(lg[i], v6, ov);
        }
        s_o[px * 17 + nh * 2 + c] = ov * inv;
    }
    __syncthreads();

    // proj 16 -> 64: thread (px, dg) computes 8 outputs, channel-planar write
    const int dg = tid >> 5;
    float my[16];
#pragma unroll
    for (int j = 0; j < 16; ++j) my[j] = s_o[px * 17 + j];
#pragma unroll
    for (int k = 0; k < 8; ++k) {
        const int d = dg * 8 + k;
        float s = s_pb[d];
#pragma unroll
        for (int j = 0; j < 16; ++j) s = fmaf(my[j], s_pw[d * 16 + j], s);
        obuf[(size_t)d * 65536 + p] = s;
    }
}

// ---------------------------------------------------------------------------
// Kernel E: fc2 (64->768) + bias + residual. TM=64, TN=128 split as
// {c0, 64+c0} so B-reads are 2-way; swizzled b128 staging (no conflicts).
// obuf read token-major (free reinterpretation).
// ---------------------------------------------------------------------------
__global__ __launch_bounds__(256) void k_fc2(
    const float* __restrict__ ot, const float* __restrict__ fc2_w,
    const float* __restrict__ fc2_b, const float* __restrict__ x,
    float* __restrict__ out)
{
    __shared__ float As[64 * 64];    // [k][t], swizzled
    __shared__ float Bs[64 * 128];   // [k][n], swizzled

    const int tid = threadIdx.x;
    const int tx = tid & 15;
    const int ty = tid >> 4;
    const int t0 = blockIdx.x * 64;
    const int n0 = blockIdx.y * 128;
    const int c0 = tx * 4;
    const int r0 = ty * 4;

    {
        float ar[4][4];
#pragma unroll
        for (int i = 0; i < 4; ++i) {
            const float4 v = *(const float4*)(ot + (size_t)(t0 + r0 + i) * 64 + c0);
            ar[i][0] = v.x; ar[i][1] = v.y; ar[i][2] = v.z; ar[i][3] = v.w;
        }
#pragma unroll
        for (int j = 0; j < 4; ++j) {
            float4 s; s.x = ar[0][j]; s.y = ar[1][j]; s.z = ar[2][j]; s.w = ar[3][j];
            *(float4*)(As + SW64(c0 + j, r0)) = s;
        }
    }
#pragma unroll
    for (int half = 0; half < 2; ++half) {
        float br[4][4];
#pragma unroll
        for (int i = 0; i < 4; ++i) {
            const float4 v = *(const float4*)(fc2_w + (size_t)(n0 + half * 64 + r0 + i) * 64 + c0);
            br[i][0] = v.x; br[i][1] = v.y; br[i][2] = v.z; br[i][3] = v.w;
        }
#pragma unroll
        for (int j = 0; j < 4; ++j) {
            float4 s; s.x = br[0][j]; s.y = br[1][j]; s.z = br[2][j]; s.w = br[3][j];
            *(float4*)(Bs + SW128(c0 + j, half * 64 + r0)) = s;
        }
    }
    __syncthreads();

    float acc[4][8];
#pragma unroll
    for (int i = 0; i < 4; ++i)
#pragma unroll
        for (int j = 0; j < 8; ++j) acc[i][j] = 0.f;

#pragma unroll 8
    for (int k = 0; k < 64; ++k) {
        const float4 a4 = *(const float4*)(As + SW64(k, r0));
        const float4 b40 = *(const float4*)(Bs + SW128(k, c0));
        const float4 b41 = *(const float4*)(Bs + SW128(k, 64 + c0));
        const float a[4] = {a4.x, a4.y, a4.z, a4.w};
        const float b[8] = {b40.x, b40.y, b40.z, b40.w, b41.x, b41.y, b41.z, b41.w};
#pragma unroll
        for (int i = 0; i < 4; ++i)
#pragma unroll
            for (int j = 0; j < 8; ++j) acc[i][j] = fmaf(a[i], b[j], acc[i][j]);
    }

    float bb[8];
#pragma unroll
    for (int j = 0; j < 4; ++j) { bb[j] = fc2_b[n0 + c0 + j]; bb[4 + j] = fc2_b[n0 + 64 + c0 + j]; }

#pragma unroll
    for (int i = 0; i < 4; ++i) {
        const size_t off = (size_t)(t0 + r0 + i) * 768 + n0;
        const float4 x0 = *(const float4*)(x + off + c0);
        const float4 x1 = *(const float4*)(x + off + 64 + c0);
        float4 o0, o1;
        o0.x = acc[i][0] + bb[0] + x0.x;
        o0.y = acc[i][1] + bb[1] + x0.y;
        o0.z = acc[i][2] + bb[2] + x0.z;
        o0.w = acc[i][3] + bb[3] + x0.w;
        o1.x = acc[i][4] + bb[4] + x1.x;
        o1.y = acc[i][5] + bb[5] + x1.y;
        o1.z = acc[i][6] + bb[6] + x1.z;
        o1.w = acc[i][7] + bb[7] + x1.w;
        *(float4*)(out + off + c0) = o0;
        *(float4*)(out + off + 64 + c0) = o1;
    }
}

// ---------------------------------------------------------------------------
extern "C" void kernel_launch(void* const* d_in, const int* in_sizes, int n_in,
                              void* d_out, int out_size, void* d_ws, size_t ws_size,
                              hipStream_t stream) {
    const float* x      = (const float*)d_in[0];
    const float* fc1_w  = (const float*)d_in[1];
    const float* fc1_b  = (const float*)d_in[2];
    const float* conv_w = (const float*)d_in[3];
    const float* conv_b = (const float*)d_in[4];
    const float* qkv_w  = (const float*)d_in[5];
    const float* qkv_b  = (const float*)d_in[6];
    const float* dep1_w = (const float*)d_in[7];
    const float* dep_b  = (const float*)d_in[8];
    const float* dep1_b = (const float*)d_in[9];
    const float* rpb    = (const float*)d_in[10];
    const float* proj_w = (const float*)d_in[11];
    const float* proj_b = (const float*)d_in[12];
    const float* fc2_w  = (const float*)d_in[13];
    const float* fc2_b  = (const float*)d_in[14];

    float* ws   = (float*)d_ws;
    float* xs   = ws;                 // 64*65536
    float* qkv  = ws + 4194304;       // 48*65536
    float* obuf = ws + 7340032;       // 64*65536
    float* out  = (float*)d_out;

    k_fc1_chain<<<dim3(1024), dim3(256), 0, stream>>>(x, fc1_w, fc1_b, conv_w, conv_b, xs);
    k_qkv<<<dim3(256, 4), dim3(256), 0, stream>>>(xs, qkv_w, qkv_b, qkv);
    k_attn<<<dim3(2048), dim3(256), 0, stream>>>(qkv, dep1_w, dep_b, dep1_b, rpb,
                                                 proj_w, proj_b, obuf);
    k_fc2<<<dim3(1024, 6), dim3(256), 0, stream>>>(obuf, fc2_w, fc2_b, x, out);
}